// Round 2
// 398.325 us; speedup vs baseline: 1.8708x; 1.8708x over previous
//
#include <hip/hip_runtime.h>
#include <hip/hip_bf16.h>

// Fused ChemicalDevelopment, v2b: latency-bound fix (resubmit of v2; round-1
// failure was a container/infra error — kernel audited for OOB/alignment/races,
// clean; only change vs v2 is dropping __builtin_amdgcn_rcpf for plain division).
//
// v1 (745us bench / 522us kernel): 512 blocks = 2/CU, 51KB LDS, scalar loads,
// 4 barriers/batch -> Occupancy 22.8%, VALUBusy 36.5%, HBM 8% (all low =
// latency-bound). v2 restructures for occupancy + instruction economy:
//  - 2048 blocks (32 strips x 64 segments of 64 rows), 128-thread (2-wave)
//    blocks, 22.8 KB LDS -> 7 blocks = 14 waves/CU resident.
//  - one PIXEL (3 channels) per thread: 3x3 coupling in registers, no inhb
//    LDS buffer, no %3, no dual-lane path.
//  - float4 staging & vertical blur (4-col halo pad makes edge masking
//    exactly float4-granular); 1 dwordx4 + 1 ds_write_b128 per row/thread.
//  - software-pipelined staging: next batch's global loads issued right
//    after the commit barrier, consumed one batch later (latency hidden
//    under vblur + epilogue).
//  - IIR warmup 32 rows (decay^32*3 = 3.4e-7, negligible vs 7.8e-3 tol).
// Math identical to v1 (same taps, same normalization, same tanh form).

#define HH 4096
#define WW 4096
#define NCH 3
#define ROWF (WW * NCH)              // 12288 elements per image row
#define WS 128                       // pixels per strip
#define NSTRIP (WW / WS)             // 32
#define HS 64                        // rows per segment
#define NSEG (HH / HS)               // 64
#define RAD 3                        // truncated blur radius
#define PADC 4                       // halo cols each side (float4-aligned)
#define IN_COLS (WS + 2 * PADC)      // 136
#define IN_LANES (IN_COLS * NCH)     // 408 floats per staged row
#define IN_V4 (IN_LANES / 4)         // 102 float4 per staged row
#define B 4                          // rows per batch
#define RINGN 10                     // ring slots (min: B + 2*RAD = 10)
#define WARM 32                      // IIR warmup rows
#define NT 128                       // threads per block (2 waves)

#define MASK_SCALE (1.0f / 3.000001f)   // 1/(D_MAX-D_MIN+1e-6) == 1/(supply+1e-6)

__device__ __forceinline__ float ldf(const float* p)          { return *p; }
__device__ __forceinline__ float ldf(const __hip_bfloat16* p) { return __bfloat162float(*p); }
__device__ __forceinline__ void  stf(float* p, float v)          { *p = v; }
__device__ __forceinline__ void  stf(__hip_bfloat16* p, float v) { *p = __float2bfloat16(v); }

__device__ __forceinline__ float4 ld4(const float* p) {
    return *reinterpret_cast<const float4*>(p);
}
__device__ __forceinline__ float4 ld4(const __hip_bfloat16* p) {
    const ushort4 u = *reinterpret_cast<const ushort4*>(p);   // 8B aligned
    float4 f;
    f.x = __uint_as_float(((unsigned)u.x) << 16);
    f.y = __uint_as_float(((unsigned)u.y) << 16);
    f.z = __uint_as_float(((unsigned)u.z) << 16);
    f.w = __uint_as_float(((unsigned)u.w) << 16);
    return f;
}

__device__ __forceinline__ int slot_of(int r) { return (r + RINGN) % RINGN; } // r >= -3

// 3*tanh(x/3.000001) via exp(-2|y|): overflow-proof, NaN-proof
__device__ __forceinline__ float tanh3(float x) {
    const float y  = x * MASK_SCALE;
    const float ay = fminf(fabsf(y), 20.0f);
    const float ex = __expf(-2.0f * ay);
    const float t  = (1.0f - ex) / (1.0f + ex);
    return copysignf(3.0f * t, y);
}

// flag[0] = 1 if buffer is plausibly bf16 (all first 4096 bf16-views in
// [0,4)), else 0 (=> float32). NaN fails the range test too.
__global__ void detect_dtype_kernel(const __hip_bfloat16* __restrict__ D,
                                    int* __restrict__ flag) {
    __shared__ int bad;
    if (threadIdx.x == 0) bad = 0;
    __syncthreads();
    for (int i = threadIdx.x; i < 4096; i += blockDim.x) {
        const float v = __bfloat162float(D[i]);
        if (!(v >= 0.0f && v < 4.0f)) bad = 1;   // benign race: all write 1
    }
    __syncthreads();
    if (threadIdx.x == 0) flag[0] = bad ? 0 : 1;
}

template <typename T>
__global__ __launch_bounds__(NT, 4)
void chemdev_kernel(const T* __restrict__ D,
                    const T* __restrict__ Cm,
                    T* __restrict__ out,
                    const int* __restrict__ flag, int want)
{
    if (flag[0] != want) return;   // wave-uniform early exit (wrong dtype)

    __shared__ float ring[RINGN][IN_LANES];   // raw rows       16320 B
    __shared__ float vbuf[B][IN_LANES];       // vblurred rows   6528 B

    const int tid = threadIdx.x;             // pixel index within strip
    const int bx  = blockIdx.x;
    const int wb  = bx * WS;                 // strip base column
    const int h0  = blockIdx.y * HS;         // segment base row

    // Gaussian weights exp(-2 x^2), normalized by the FULL 25-tap sum like
    // the reference (taps |x| in [4,12] contribute ~2.5e-14 -> ignored).
    const float e1 = expf(-2.0f);
    const float e2 = expf(-8.0f);
    const float e3 = expf(-18.0f);
    const float e4 = expf(-32.0f);
    const float ksum = 1.0f + 2.0f * (e1 + e2 + e3 + e4);
    const float kc = 1.0f / ksum;
    const float k1 = e1 / ksum;
    const float k2 = e2 / ksum;
    const float k3 = e3 / ksum;

    const float decay = expf(-0.5f);   // clip(..,0,0.999) is a no-op
    const float omd   = 1.0f - decay;

    float C[9];
    #pragma unroll
    for (int i = 0; i < 9; i++) C[i] = ldf(&Cm[i]);

    // ---- float4 staging geometry (edge masking is float4-granular:
    //      4 pad cols = 12 floats = exactly 3 float4s) ----
    const int  lo4 = (bx == 0)          ? RAD        : 0;      // cols < 0
    const int  hi4 = (bx == NSTRIP - 1) ? IN_V4 - RAD : IN_V4; // cols >= WW
    const bool stg = (tid < IN_V4);
    const long colbase = (long)wb * NCH - PADC * NCH + 4 * tid;

    auto fetch_row = [&](int r) -> float4 {
        float4 v = make_float4(0.f, 0.f, 0.f, 0.f);
        if (r >= 0 && r < HH && tid >= lo4 && tid < hi4)
            v = ld4(&D[(long)r * ROWF + colbase]);
        return v;
    };
    auto commit_row = [&](int r, float4 v) {
        if (stg)
            *reinterpret_cast<float4*>(&ring[slot_of(r)][4 * tid]) = v;
    };

    // ---- IIR warmup: per-pixel carries from the 32 rows above ----
    float c0 = 0.f, c1 = 0.f, c2 = 0.f;
    if (h0 > 0) {
        const long pixbase = (long)wb * NCH + 3 * tid;
        for (int r = h0 - WARM; r < h0; r += 4) {
            float d[12];
            #pragma unroll
            for (int q = 0; q < 4; q++) {
                const long base = (long)(r + q) * ROWF + pixbase;
                d[3*q+0] = ldf(&D[base + 0]);
                d[3*q+1] = ldf(&D[base + 1]);
                d[3*q+2] = ldf(&D[base + 2]);
            }
            #pragma unroll
            for (int q = 0; q < 4; q++) {
                c0 = fmaf(decay, c0, d[3*q+0]);
                c1 = fmaf(decay, c1, d[3*q+1]);
                c2 = fmaf(decay, c2, d[3*q+2]);
            }
        }
    }

    // ---- preload halo rows h0-3 .. h0+2 into ring; stage h0+3..h0+6 ----
    #pragma unroll
    for (int q = 0; q < 2 * RAD; q++) {
        const int r = h0 - RAD + q;
        commit_row(r, fetch_row(r));
    }
    float4 rv0 = fetch_row(h0 + 3);
    float4 rv1 = fetch_row(h0 + 4);
    float4 rv2 = fetch_row(h0 + 5);
    float4 rv3 = fetch_row(h0 + 6);

    // ---- main loop: 3 barriers per 4-row batch ----
    for (int hb = h0; hb < h0 + HS; hb += B) {
        // (a) commit staged rows hb+3..hb+6 (evicts rows hb-7..hb-4, whose
        //     last readers were fenced by barrier (g) of the previous batch)
        commit_row(hb + 3, rv0);
        commit_row(hb + 4, rv1);
        commit_row(hb + 5, rv2);
        commit_row(hb + 6, rv3);
        __syncthreads();                        // (b) ring hb-3..hb+6 visible

        // (c) issue next batch's loads NOW; consumed at (a) next iteration,
        //     so the global latency hides under vblur + epilogue below.
        if (hb + B < h0 + HS) {
            rv0 = fetch_row(hb + 7);
            rv1 = fetch_row(hb + 8);
            rv2 = fetch_row(hb + 9);
            rv3 = fetch_row(hb + 10);
        }

        // (d) vertical 7-tap blur, float4-packed
        if (stg) {
            const int o = 4 * tid;
            #pragma unroll
            for (int rr = 0; rr < B; rr++) {
                const int sb = hb + rr;
                const float4 a0 = *reinterpret_cast<const float4*>(&ring[slot_of(sb - 3)][o]);
                const float4 a1 = *reinterpret_cast<const float4*>(&ring[slot_of(sb - 2)][o]);
                const float4 a2 = *reinterpret_cast<const float4*>(&ring[slot_of(sb - 1)][o]);
                const float4 a3 = *reinterpret_cast<const float4*>(&ring[slot_of(sb    )][o]);
                const float4 a4 = *reinterpret_cast<const float4*>(&ring[slot_of(sb + 1)][o]);
                const float4 a5 = *reinterpret_cast<const float4*>(&ring[slot_of(sb + 2)][o]);
                const float4 a6 = *reinterpret_cast<const float4*>(&ring[slot_of(sb + 3)][o]);
                float4 acc;
                acc.x = fmaf(k3, a0.x + a6.x, fmaf(k2, a1.x + a5.x, fmaf(k1, a2.x + a4.x, kc * a3.x)));
                acc.y = fmaf(k3, a0.y + a6.y, fmaf(k2, a1.y + a5.y, fmaf(k1, a2.y + a4.y, kc * a3.y)));
                acc.z = fmaf(k3, a0.z + a6.z, fmaf(k2, a1.z + a5.z, fmaf(k1, a2.z + a4.z, kc * a3.z)));
                acc.w = fmaf(k3, a0.w + a6.w, fmaf(k2, a1.w + a5.w, fmaf(k1, a2.w + a4.w, kc * a3.w)));
                *reinterpret_cast<float4*>(&vbuf[rr][o]) = acc;
            }
        }
        __syncthreads();                        // (e) vbuf ready

        // (f) per-pixel epilogue: hblur + IIR + blend + coupling + tanh
        //     Thread owns pixel (wb+tid), channels ch at lane 12+3*tid+ch.
        {
            const int b3 = 3 * tid;
            #pragma unroll
            for (int rr = 0; rr < B; rr++) {
                const int row = hb + rr;
                const float* v  = vbuf[rr];
                const float* rw = ring[slot_of(row)];

                float hv[21];                        // lanes b3+3 .. b3+23
                #pragma unroll
                for (int j = 0; j < 21; j++) hv[j] = v[b3 + 3 + j];
                // channel ch center = hv[9+ch]; tap dx -> hv[9+ch+3*dx]
                const float hA = fmaf(k3, hv[0] + hv[18], fmaf(k2, hv[3] + hv[15], fmaf(k1, hv[6] + hv[12], kc * hv[9])));
                const float hB = fmaf(k3, hv[1] + hv[19], fmaf(k2, hv[4] + hv[16], fmaf(k1, hv[7] + hv[13], kc * hv[10])));
                const float hC = fmaf(k3, hv[2] + hv[20], fmaf(k2, hv[5] + hv[17], fmaf(k1, hv[8] + hv[14], kc * hv[11])));

                const float d0 = rw[b3 + 12];
                const float d1 = rw[b3 + 13];
                const float d2 = rw[b3 + 14];
                c0 = fmaf(decay, c0, d0);
                c1 = fmaf(decay, c1, d1);
                c2 = fmaf(decay, c2, d2);

                const float m0 = fminf(fmaxf(d0 * MASK_SCALE, 0.f), 1.f);
                const float m1 = fminf(fmaxf(d1 * MASK_SCALE, 0.f), 1.f);
                const float m2 = fminf(fmaxf(d2 * MASK_SCALE, 0.f), 1.f);
                const float i0 = hA * m0 + omd * c0 * (1.f - m0);
                const float i1 = hB * m1 + omd * c1 * (1.f - m1);
                const float i2 = hC * m2 + omd * c2 * (1.f - m2);

                // einsum('ij,hwi->hwj'): n_j = sum_i C[i*3+j] * inh_i
                const float n0 = fmaf(C[0], i0, fmaf(C[3], i1, C[6] * i2));
                const float n1 = fmaf(C[1], i0, fmaf(C[4], i1, C[7] * i2));
                const float n2 = fmaf(C[2], i0, fmaf(C[5], i1, C[8] * i2));

                const long ob = (long)row * ROWF + (long)wb * NCH + b3;
                stf(&out[ob + 0], tanh3(d0 - n0));
                stf(&out[ob + 1], tanh3(d1 - n1));
                stf(&out[ob + 2], tanh3(d2 - n2));
            }
        }
        __syncthreads();   // (g) rows hb..hb+3 free before next commit
    }
}

extern "C" void kernel_launch(void* const* d_in, const int* in_sizes, int n_in,
                              void* d_out, int out_size, void* d_ws, size_t ws_size,
                              hipStream_t stream) {
    int* flag = (int*)d_ws;
    detect_dtype_kernel<<<1, 256, 0, stream>>>(
        (const __hip_bfloat16*)d_in[0], flag);

    dim3 grid(NSTRIP, NSEG);   // 32 x 64 = 2048 blocks

    // bf16 interpretation (runs iff flag==1)
    chemdev_kernel<__hip_bfloat16><<<grid, NT, 0, stream>>>(
        (const __hip_bfloat16*)d_in[0], (const __hip_bfloat16*)d_in[1],
        (__hip_bfloat16*)d_out, flag, 1);

    // float32 interpretation (runs iff flag==0)
    chemdev_kernel<float><<<grid, NT, 0, stream>>>(
        (const float*)d_in[0], (const float*)d_in[1],
        (float*)d_out, flag, 0);
}

// Round 3
// 387.063 us; speedup vs baseline: 1.9252x; 1.0291x over previous
//
#include <hip/hip_runtime.h>
#include <hip/hip_bf16.h>

// Fused ChemicalDevelopment, v3: residency-quantization fix.
// v2b (398us bench / 166us kernel): 23KB LDS -> 7 resident blocks/CU but grid
// assigns exactly 8/CU -> the 8th block runs nearly alone (measured occupancy
// 28.5% ~= avg of 43.75% and 6.25% phases). Kernel time ~2 block-generations.
// v3: B=4->2, RINGN=10->8 => LDS 16320B (alloc 16384) -> 10 blocks/CU capacity,
// all 8 assigned blocks resident at once, zero tail. Prefetch issue moved
// before the commit barrier so global latency drains during the barrier wait.
// Math identical to v2b (same taps, normalization, tanh, warmup).

#define HH 4096
#define WW 4096
#define NCH 3
#define ROWF (WW * NCH)              // 12288 elements per image row
#define WS 128                       // pixels per strip
#define NSTRIP (WW / WS)             // 32
#define HS 64                        // rows per segment
#define NSEG (HH / HS)               // 64
#define RAD 3                        // truncated blur radius
#define PADC 4                       // halo cols each side (float4-aligned)
#define IN_COLS (WS + 2 * PADC)      // 136
#define IN_LANES (IN_COLS * NCH)     // 408 floats per staged row
#define IN_V4 (IN_LANES / 4)         // 102 float4 per staged row
#define B 2                          // rows per batch
#define RINGN 8                      // ring slots (= B + 2*RAD, power of 2)
#define WARM 32                      // IIR warmup rows
#define NT 128                       // threads per block (2 waves)

#define MASK_SCALE (1.0f / 3.000001f)   // 1/(D_MAX-D_MIN+1e-6) == 1/(supply+1e-6)

__device__ __forceinline__ float ldf(const float* p)          { return *p; }
__device__ __forceinline__ float ldf(const __hip_bfloat16* p) { return __bfloat162float(*p); }
__device__ __forceinline__ void  stf(float* p, float v)          { *p = v; }
__device__ __forceinline__ void  stf(__hip_bfloat16* p, float v) { *p = __float2bfloat16(v); }

__device__ __forceinline__ float4 ld4(const float* p) {
    return *reinterpret_cast<const float4*>(p);
}
__device__ __forceinline__ float4 ld4(const __hip_bfloat16* p) {
    const ushort4 u = *reinterpret_cast<const ushort4*>(p);   // 8B aligned
    float4 f;
    f.x = __uint_as_float(((unsigned)u.x) << 16);
    f.y = __uint_as_float(((unsigned)u.y) << 16);
    f.z = __uint_as_float(((unsigned)u.z) << 16);
    f.w = __uint_as_float(((unsigned)u.w) << 16);
    return f;
}

__device__ __forceinline__ int slot_of(int r) { return (r + RINGN) & (RINGN - 1); } // r >= -3

// 3*tanh(x/3.000001) via exp(-2|y|): overflow-proof, NaN-proof
__device__ __forceinline__ float tanh3(float x) {
    const float y  = x * MASK_SCALE;
    const float ay = fminf(fabsf(y), 20.0f);
    const float ex = __expf(-2.0f * ay);
    const float t  = (1.0f - ex) / (1.0f + ex);
    return copysignf(3.0f * t, y);
}

// flag[0] = 1 if buffer is plausibly bf16 (all first 4096 bf16-views in
// [0,4)), else 0 (=> float32). NaN fails the range test too.
__global__ void detect_dtype_kernel(const __hip_bfloat16* __restrict__ D,
                                    int* __restrict__ flag) {
    __shared__ int bad;
    if (threadIdx.x == 0) bad = 0;
    __syncthreads();
    for (int i = threadIdx.x; i < 4096; i += blockDim.x) {
        const float v = __bfloat162float(D[i]);
        if (!(v >= 0.0f && v < 4.0f)) bad = 1;   // benign race: all write 1
    }
    __syncthreads();
    if (threadIdx.x == 0) flag[0] = bad ? 0 : 1;
}

template <typename T>
__global__ __launch_bounds__(NT, 4)
void chemdev_kernel(const T* __restrict__ D,
                    const T* __restrict__ Cm,
                    T* __restrict__ out,
                    const int* __restrict__ flag, int want)
{
    if (flag[0] != want) return;   // wave-uniform early exit (wrong dtype)

    __shared__ float ring[RINGN][IN_LANES];   // raw rows       13056 B
    __shared__ float vbuf[B][IN_LANES];       // vblurred rows   3264 B

    const int tid = threadIdx.x;             // pixel index within strip
    const int bx  = blockIdx.x;
    const int wb  = bx * WS;                 // strip base column
    const int h0  = blockIdx.y * HS;         // segment base row

    // Gaussian weights exp(-2 x^2), normalized by the FULL 25-tap sum like
    // the reference (taps |x| in [4,12] contribute ~2.5e-14 -> ignored).
    const float e1 = expf(-2.0f);
    const float e2 = expf(-8.0f);
    const float e3 = expf(-18.0f);
    const float e4 = expf(-32.0f);
    const float ksum = 1.0f + 2.0f * (e1 + e2 + e3 + e4);
    const float kc = 1.0f / ksum;
    const float k1 = e1 / ksum;
    const float k2 = e2 / ksum;
    const float k3 = e3 / ksum;

    const float decay = expf(-0.5f);   // clip(..,0,0.999) is a no-op
    const float omd   = 1.0f - decay;

    float C[9];
    #pragma unroll
    for (int i = 0; i < 9; i++) C[i] = ldf(&Cm[i]);

    // ---- float4 staging geometry (edge masking is float4-granular:
    //      4 pad cols = 12 floats = exactly 3 float4s) ----
    const int  lo4 = (bx == 0)          ? RAD        : 0;      // cols < 0
    const int  hi4 = (bx == NSTRIP - 1) ? IN_V4 - RAD : IN_V4; // cols >= WW
    const bool stg = (tid < IN_V4);
    const long colbase = (long)wb * NCH - PADC * NCH + 4 * tid;

    auto fetch_row = [&](int r) -> float4 {
        float4 v = make_float4(0.f, 0.f, 0.f, 0.f);
        if (r >= 0 && r < HH && tid >= lo4 && tid < hi4)
            v = ld4(&D[(long)r * ROWF + colbase]);
        return v;
    };
    auto commit_row = [&](int r, float4 v) {
        if (stg)
            *reinterpret_cast<float4*>(&ring[slot_of(r)][4 * tid]) = v;
    };

    // ---- IIR warmup: per-pixel carries from the 32 rows above ----
    float c0 = 0.f, c1 = 0.f, c2 = 0.f;
    if (h0 > 0) {
        const long pixbase = (long)wb * NCH + 3 * tid;
        for (int r = h0 - WARM; r < h0; r += 4) {
            float d[12];
            #pragma unroll
            for (int q = 0; q < 4; q++) {
                const long base = (long)(r + q) * ROWF + pixbase;
                d[3*q+0] = ldf(&D[base + 0]);
                d[3*q+1] = ldf(&D[base + 1]);
                d[3*q+2] = ldf(&D[base + 2]);
            }
            #pragma unroll
            for (int q = 0; q < 4; q++) {
                c0 = fmaf(decay, c0, d[3*q+0]);
                c1 = fmaf(decay, c1, d[3*q+1]);
                c2 = fmaf(decay, c2, d[3*q+2]);
            }
        }
    }

    // ---- preload halo rows h0-3 .. h0+2 into ring; stage h0+3, h0+4 ----
    #pragma unroll
    for (int q = 0; q < 2 * RAD; q++) {
        const int r = h0 - RAD + q;
        commit_row(r, fetch_row(r));
    }
    float4 rv0 = fetch_row(h0 + 3);
    float4 rv1 = fetch_row(h0 + 4);

    // ---- main loop: 3 barriers per 2-row batch ----
    // Ring invariant: batch hb needs rows hb-3..hb+4 (8 = RINGN slots).
    // Commit of hb+3/hb+4 evicts slots of hb-5/hb-4, whose last readers
    // (vblur of batch hb-2) were fenced by that batch's final barrier.
    for (int hb = h0; hb < h0 + HS; hb += B) {
        // (a) commit staged rows hb+3, hb+4
        commit_row(hb + 3, rv0);
        commit_row(hb + 4, rv1);

        // (b) issue next batch's loads BEFORE the barrier: register-targeted,
        //     no LDS interaction; latency drains during the barrier wait and
        //     the compute below. WAR on rv regs is handled by the compiler.
        if (hb + B < h0 + HS) {
            rv0 = fetch_row(hb + 5);
            rv1 = fetch_row(hb + 6);
        }
        __syncthreads();                        // (c) ring hb-3..hb+4 visible

        // (d) vertical 7-tap blur, float4-packed
        if (stg) {
            const int o = 4 * tid;
            #pragma unroll
            for (int rr = 0; rr < B; rr++) {
                const int sb = hb + rr;
                const float4 a0 = *reinterpret_cast<const float4*>(&ring[slot_of(sb - 3)][o]);
                const float4 a1 = *reinterpret_cast<const float4*>(&ring[slot_of(sb - 2)][o]);
                const float4 a2 = *reinterpret_cast<const float4*>(&ring[slot_of(sb - 1)][o]);
                const float4 a3 = *reinterpret_cast<const float4*>(&ring[slot_of(sb    )][o]);
                const float4 a4 = *reinterpret_cast<const float4*>(&ring[slot_of(sb + 1)][o]);
                const float4 a5 = *reinterpret_cast<const float4*>(&ring[slot_of(sb + 2)][o]);
                const float4 a6 = *reinterpret_cast<const float4*>(&ring[slot_of(sb + 3)][o]);
                float4 acc;
                acc.x = fmaf(k3, a0.x + a6.x, fmaf(k2, a1.x + a5.x, fmaf(k1, a2.x + a4.x, kc * a3.x)));
                acc.y = fmaf(k3, a0.y + a6.y, fmaf(k2, a1.y + a5.y, fmaf(k1, a2.y + a4.y, kc * a3.y)));
                acc.z = fmaf(k3, a0.z + a6.z, fmaf(k2, a1.z + a5.z, fmaf(k1, a2.z + a4.z, kc * a3.z)));
                acc.w = fmaf(k3, a0.w + a6.w, fmaf(k2, a1.w + a5.w, fmaf(k1, a2.w + a4.w, kc * a3.w)));
                *reinterpret_cast<float4*>(&vbuf[rr][o]) = acc;
            }
        }
        __syncthreads();                        // (e) vbuf ready

        // (f) per-pixel epilogue: hblur + IIR + blend + coupling + tanh
        //     Thread owns pixel (wb+tid), channels ch at lane 12+3*tid+ch.
        {
            const int b3 = 3 * tid;
            #pragma unroll
            for (int rr = 0; rr < B; rr++) {
                const int row = hb + rr;
                const float* v  = vbuf[rr];
                const float* rw = ring[slot_of(row)];

                float hv[21];                        // lanes b3+3 .. b3+23
                #pragma unroll
                for (int j = 0; j < 21; j++) hv[j] = v[b3 + 3 + j];
                // channel ch center = hv[9+ch]; tap dx -> hv[9+ch+3*dx]
                const float hA = fmaf(k3, hv[0] + hv[18], fmaf(k2, hv[3] + hv[15], fmaf(k1, hv[6] + hv[12], kc * hv[9])));
                const float hB = fmaf(k3, hv[1] + hv[19], fmaf(k2, hv[4] + hv[16], fmaf(k1, hv[7] + hv[13], kc * hv[10])));
                const float hC = fmaf(k3, hv[2] + hv[20], fmaf(k2, hv[5] + hv[17], fmaf(k1, hv[8] + hv[14], kc * hv[11])));

                const float d0 = rw[b3 + 12];
                const float d1 = rw[b3 + 13];
                const float d2 = rw[b3 + 14];
                c0 = fmaf(decay, c0, d0);
                c1 = fmaf(decay, c1, d1);
                c2 = fmaf(decay, c2, d2);

                const float m0 = fminf(fmaxf(d0 * MASK_SCALE, 0.f), 1.f);
                const float m1 = fminf(fmaxf(d1 * MASK_SCALE, 0.f), 1.f);
                const float m2 = fminf(fmaxf(d2 * MASK_SCALE, 0.f), 1.f);
                const float i0 = hA * m0 + omd * c0 * (1.f - m0);
                const float i1 = hB * m1 + omd * c1 * (1.f - m1);
                const float i2 = hC * m2 + omd * c2 * (1.f - m2);

                // einsum('ij,hwi->hwj'): n_j = sum_i C[i*3+j] * inh_i
                const float n0 = fmaf(C[0], i0, fmaf(C[3], i1, C[6] * i2));
                const float n1 = fmaf(C[1], i0, fmaf(C[4], i1, C[7] * i2));
                const float n2 = fmaf(C[2], i0, fmaf(C[5], i1, C[8] * i2));

                const long ob = (long)row * ROWF + (long)wb * NCH + b3;
                stf(&out[ob + 0], tanh3(d0 - n0));
                stf(&out[ob + 1], tanh3(d1 - n1));
                stf(&out[ob + 2], tanh3(d2 - n2));
            }
        }
        __syncthreads();   // (g) rows hb, hb+1 free before next commit
    }
}

extern "C" void kernel_launch(void* const* d_in, const int* in_sizes, int n_in,
                              void* d_out, int out_size, void* d_ws, size_t ws_size,
                              hipStream_t stream) {
    int* flag = (int*)d_ws;
    detect_dtype_kernel<<<1, 256, 0, stream>>>(
        (const __hip_bfloat16*)d_in[0], flag);

    dim3 grid(NSTRIP, NSEG);   // 32 x 64 = 2048 blocks

    // bf16 interpretation (runs iff flag==1)
    chemdev_kernel<__hip_bfloat16><<<grid, NT, 0, stream>>>(
        (const __hip_bfloat16*)d_in[0], (const __hip_bfloat16*)d_in[1],
        (__hip_bfloat16*)d_out, flag, 1);

    // float32 interpretation (runs iff flag==0)
    chemdev_kernel<float><<<grid, NT, 0, stream>>>(
        (const float*)d_in[0], (const float*)d_in[1],
        (float*)d_out, flag, 0);
}